// Round 1
// 453.525 us; speedup vs baseline: 1.0748x; 1.0748x over previous
//
#include <hip/hip_runtime.h>
#include <math.h>

// Transformer-XL relative attention, bf16-MFMA, fused-softmax version.
// B=4 N=16 L=1024 D=64. Outputs: out [B,N,L,D] fp32, then weight [B,N,L,L] fp32.
// rel_shift(pos)[i,j] == pos[i, j - i + (L-1)], only j<=i survives the causal mask.
//
// R1: 512-thread blocks (8 waves, same 66KB score LDS -> 2 blocks/CU = 16 waves/CU,
//     was 8) + XCD-contiguous blockIdx swizzle (same-bn blocks share one L2) +
//     split-k Phase D across wave pairs. Attacks latency-boundedness
//     (MfmaUtil 2.4%, VALUBusy 22%, HBM 23%, Occ 17% -> nothing saturated).

#define Bq 4
#define Nh 16
#define Lq 1024
#define Dh 64
#define TQ 16     // query rows per block
#define NT 512    // 8 waves
#define LPAD 1028 // fp32 row stride in LDS (bytes: 4112); +4 pad -> 2-way banks (free)

typedef __attribute__((ext_vector_type(8))) short bf16x8;
typedef __attribute__((ext_vector_type(4))) float f32x4;

__device__ __forceinline__ unsigned short f2bf(float f) {
    union { float f; unsigned int u; } v; v.f = f;
    unsigned int u = v.u;
    unsigned int r = u + 0x7FFFu + ((u >> 16) & 1u);  // RNE
    return (unsigned short)(r >> 16);
}

__device__ __forceinline__ bf16x8 pack8(float4 a, float4 b) {
    bf16x8 o;
    o[0] = (short)f2bf(a.x); o[1] = (short)f2bf(a.y);
    o[2] = (short)f2bf(a.z); o[3] = (short)f2bf(a.w);
    o[4] = (short)f2bf(b.x); o[5] = (short)f2bf(b.y);
    o[6] = (short)f2bf(b.z); o[7] = (short)f2bf(b.w);
    return o;
}

__device__ __forceinline__ bf16x8 ldg8(const unsigned short* p) {
    return *(const bf16x8*)p;
}

__device__ __forceinline__ float wave_max(float v) {
    #pragma unroll
    for (int o = 32; o > 0; o >>= 1) v = fmaxf(v, __shfl_xor(v, o));
    return v;
}
__device__ __forceinline__ float wave_sum(float v) {
    #pragma unroll
    for (int o = 32; o > 0; o >>= 1) v += __shfl_xor(v, o);
    return v;
}

// ---------- prep: K and P fp32 -> bf16 (one kernel, two ranges) ----------
__global__ __launch_bounds__(256) void cvt_kp_kernel(
    const float* __restrict__ K, const float* __restrict__ P,
    unsigned short* __restrict__ Kb, unsigned short* __restrict__ Pb)
{
    int b = blockIdx.x;
    const float* src; unsigned short* dst; int idx;
    if (b < 4096) { idx = b * 256 + threadIdx.x; src = K; dst = Kb; }
    else          { idx = (b - 4096) * 256 + threadIdx.x; src = P; dst = Pb; }
    float4 v = ((const float4*)src)[idx];
    ushort4 o;
    o.x = f2bf(v.x); o.y = f2bf(v.y); o.z = f2bf(v.z); o.w = f2bf(v.w);
    ((ushort4*)dst)[idx] = o;
}

// ---------- prep: V [bn][j][d] fp32 -> Vt [bn][d][j] bf16 ----------
__global__ __launch_bounds__(256) void vt_kernel(
    const float* __restrict__ V, unsigned short* __restrict__ Vt)
{
    __shared__ float t[64][65];
    int bn = blockIdx.x >> 4, jt = blockIdx.x & 15;
    int tid = threadIdx.x;
    int d = tid & 63, q = tid >> 6;
    const float* vb = V + ((size_t)(bn * Lq + jt * 64)) * Dh;
    #pragma unroll
    for (int r = 0; r < 16; r++) {
        int jl = r * 4 + q;
        t[jl][d] = vb[(size_t)jl * Dh + d];
    }
    __syncthreads();
    int dd = tid >> 2, jb = (tid & 3) << 4;
    bf16x8 s0, s1;
    #pragma unroll
    for (int jj = 0; jj < 8; jj++) {
        s0[jj] = (short)f2bf(t[jb + jj][dd]);
        s1[jj] = (short)f2bf(t[jb + 8 + jj][dd]);
    }
    unsigned short* drow = Vt + (((size_t)(bn * 64 + dd)) << 10) + (jt << 6) + jb;
    *(bf16x8*)drow = s0;
    *(bf16x8*)(drow + 8) = s1;
}

// ---------- main ----------
__global__ __launch_bounds__(NT, 4) void relattn_kernel(
    const float* __restrict__ QC, const float* __restrict__ QP,
    const unsigned short* __restrict__ Kb, const unsigned short* __restrict__ Pb,
    const unsigned short* __restrict__ Vtb,
    float* __restrict__ out, float* __restrict__ wout)
{
    __shared__ __align__(16) float s_s[TQ][LPAD];   // 65792 B
    __shared__ __align__(16) float dscr[4][64][4];  // 4096 B, Phase D split-k combine

    const int tid  = threadIdx.x;
    const int w    = tid >> 6, lane = tid & 63;
    const int ln   = lane & 15, quad = lane >> 4;

    // XCD-contiguous remap: 4096 blocks, 8 XCDs -> 512 consecutive work items per XCD
    // (all 64 query-tiles of bn 0..7 land on XCD0, etc -> Kb/Vtb/Pb stay L2-hot).
    const int bidx = blockIdx.x;
    const int wg   = ((bidx & 7) << 9) | (bidx >> 3);
    const int bn   = wg >> 6, qt = wg & 63;
    const int nh   = bn & 15;
    const int i0   = qt << 4, i1 = i0 + 15;

    // A fragments from fp32 directly: A[m=ln][k=quad*8+j]
    const float* qcrow = QC + (((size_t)(bn << 10) + i0 + ln) << 6) + (quad << 3);
    const float* qprow = QP + (((size_t)(bn << 10) + i0 + ln) << 6) + (quad << 3);
    bf16x8 aC0 = pack8(*(const float4*)qcrow,        *(const float4*)(qcrow + 4));
    bf16x8 aC1 = pack8(*(const float4*)(qcrow + 32), *(const float4*)(qcrow + 36));
    bf16x8 aP0 = pack8(*(const float4*)qprow,        *(const float4*)(qprow + 4));
    bf16x8 aP1 = pack8(*(const float4*)(qprow + 32), *(const float4*)(qprow + 36));

    // ---- Phase A: content scores S = QC . K^T (causal tiles only) ----
    const unsigned short* kbase = Kb + (((size_t)(bn << 10)) << 6) + (quad << 3);
    #pragma unroll
    for (int ct = 0; ct < 8; ct++) {
        int c0 = ((ct << 3) + w) << 4;           // interleave tiles across 8 waves
        if (c0 <= i1) {
            const unsigned short* kr = kbase + ((size_t)(c0 + ln) << 6);
            f32x4 acc = {0.f, 0.f, 0.f, 0.f};
            acc = __builtin_amdgcn_mfma_f32_16x16x32_bf16(aC0, ldg8(kr),      acc, 0, 0, 0);
            acc = __builtin_amdgcn_mfma_f32_16x16x32_bf16(aC1, ldg8(kr + 32), acc, 0, 0, 0);
            #pragma unroll
            for (int rg = 0; rg < 4; rg++)        // C: col=ln, row=quad*4+rg
                s_s[(quad << 2) + rg][c0 + ln] = acc[rg];
        }
    }
    __syncthreads();

    // ---- Phase B: pos scores T = QP . P^T, scatter-add with rel_shift ----
    const unsigned short* pbase = Pb + (((size_t)(nh << 10)) << 6) + (quad << 3);
    #pragma unroll
    for (int ct = 0; ct < 8; ct++) {
        int p0 = ((ct << 3) + w) << 4;
        if (p0 + i0 + 30 >= 1023) {              // some j = p+i-1023 >= 0 in tile
            const unsigned short* pr = pbase + ((size_t)(p0 + ln) << 6);
            f32x4 acc = {0.f, 0.f, 0.f, 0.f};
            acc = __builtin_amdgcn_mfma_f32_16x16x32_bf16(aP0, ldg8(pr),      acc, 0, 0, 0);
            acc = __builtin_amdgcn_mfma_f32_16x16x32_bf16(aP1, ldg8(pr + 32), acc, 0, 0, 0);
            int p = p0 + ln;
            #pragma unroll
            for (int rg = 0; rg < 4; rg++) {
                int row = (quad << 2) + rg;
                int j = p + i0 + row - 1023;     // j <= i always (p <= 1023)
                if (j >= 0) s_s[row][j] += acc[rg];   // unique (row,j) per lane: no race
            }
        }
    }
    __syncthreads();

    // ---- Phase C: in-register softmax; write W fp32; pack bf16 weights in-place ----
    // Wave w owns rows 2w, 2w+1. Lane owns j = c*256 + lane*4 + e, c=0..3, e=0..3.
    #pragma unroll
    for (int rr = 0; rr < 2; rr++) {
        int r = (w << 1) + rr;
        int i = i0 + r;
        float v[16];
        #pragma unroll
        for (int c = 0; c < 4; c++) {
            float4 t = *(float4*)&s_s[r][(c << 8) + (lane << 2)];
            v[c * 4 + 0] = t.x; v[c * 4 + 1] = t.y;
            v[c * 4 + 2] = t.z; v[c * 4 + 3] = t.w;
        }
        float mx = -3.0e38f;
        #pragma unroll
        for (int c = 0; c < 4; c++) {
            int j = (c << 8) + (lane << 2);
            #pragma unroll
            for (int e = 0; e < 4; e++)
                if (j + e <= i) mx = fmaxf(mx, v[c * 4 + e]);
        }
        mx = wave_max(mx);
        float sum = 0.f;
        #pragma unroll
        for (int c = 0; c < 4; c++) {
            int j = (c << 8) + (lane << 2);
            #pragma unroll
            for (int e = 0; e < 4; e++) {
                float t = (j + e <= i) ? __expf((v[c * 4 + e] - mx) * 0.125f) : 0.f;
                sum += t;
                v[c * 4 + e] = t;
            }
        }
        sum = wave_sum(sum);
        float inv = 1.0f / sum;
        float* wrow = wout + (((size_t)(bn << 10) + i) << 10);
        char*  brow = (char*)s_s + (size_t)r * (LPAD * 4);   // bf16 row, in-place
        #pragma unroll
        for (int c = 0; c < 4; c++) {
            int j = (c << 8) + (lane << 2);
            float4 e;
            e.x = v[c * 4 + 0] * inv; e.y = v[c * 4 + 1] * inv;
            e.z = v[c * 4 + 2] * inv; e.w = v[c * 4 + 3] * inv;
            *(float4*)&wrow[j] = e;              // W output (coalesced, zeros in mask)
            ushort4 h;
            h.x = f2bf(e.x); h.y = f2bf(e.y); h.z = f2bf(e.z); h.w = f2bf(e.w);
            *(ushort4*)(brow + (size_t)j * 2) = h;   // bf16 A-operand for Phase D
        }
    }
    __syncthreads();

    // ---- Phase D: out = W . V via MFMA, split-k across wave pairs ----
    // Wave (w&3) owns output cols n0..n0+15; half h = w>>2 takes every other k-step.
    f32x4 o = {0.f, 0.f, 0.f, 0.f};
    const int n0 = (w & 3) << 4;
    const int h  = w >> 2;
    const unsigned short* vtb = Vtb + (((size_t)(bn << 6) + n0 + ln) << 10);
    const char* abase = (const char*)s_s + (size_t)ln * (LPAD * 4);
    const int ksteps = (i0 + 16 + 31) >> 5;       // j <= i1 only; rest of W is 0
    for (int ks = h; ks < ksteps; ks += 2) {
        int k0 = (ks << 5) + (quad << 3);
        bf16x8 af = *(const bf16x8*)(abase + (size_t)k0 * 2);
        bf16x8 vb = ldg8(vtb + k0);
        o = __builtin_amdgcn_mfma_f32_16x16x32_bf16(af, vb, o, 0, 0, 0);
    }
    if (h == 1)
        *(f32x4*)&dscr[w & 3][lane][0] = o;
    __syncthreads();
    if (h == 0) {
        f32x4 o2 = *(f32x4*)&dscr[w][lane][0];
        o[0] += o2[0]; o[1] += o2[1]; o[2] += o2[2]; o[3] += o2[3];
        float* obase = out + (((size_t)(bn << 10) + i0) << 6);
        #pragma unroll
        for (int rg = 0; rg < 4; rg++)
            obase[((size_t)((quad << 2) + rg) << 6) + n0 + ln] = o[rg];
    }
}

extern "C" void kernel_launch(void* const* d_in, const int* in_sizes, int n_in,
                              void* d_out, int out_size, void* d_ws, size_t ws_size,
                              hipStream_t stream) {
    const float* qc = (const float*)d_in[0];
    const float* qp = (const float*)d_in[1];
    const float* K  = (const float*)d_in[2];
    const float* V  = (const float*)d_in[3];
    const float* P  = (const float*)d_in[4];
    // d_in[5]: causal mask, hardcoded.

    float* out  = (float*)d_out;
    float* wout = out + (size_t)Bq * Nh * Lq * Dh;

    const size_t NQ = (size_t)Bq * Nh * Lq * Dh;   // 4,194,304
    const size_t NP = (size_t)Nh * Lq * Dh;        // 1,048,576
    unsigned short* Kb  = (unsigned short*)d_ws;
    unsigned short* Pb  = Kb + NQ;
    unsigned short* Vtb = Pb + NP;                 // total 18 MB of ws

    cvt_kp_kernel<<<4096 + 1024, 256, 0, stream>>>(K, P, Kb, Pb);
    vt_kernel<<<Bq * Nh * 16, 256, 0, stream>>>(V, Vtb);
    relattn_kernel<<<Bq * Nh * (Lq / TQ), NT, 0, stream>>>(qc, qp, Kb, Pb, Vtb, out, wout);
}

// Round 2
// 444.667 us; speedup vs baseline: 1.0962x; 1.0199x over previous
//
#include <hip/hip_runtime.h>
#include <math.h>

// Transformer-XL relative attention, fp16-MFMA, fused-softmax version.
// B=4 N=16 L=1024 D=64. Outputs: out [B,N,L,D] fp32, then weight [B,N,L,L] fp32.
// rel_shift(pos)[i,j] == pos[i, j - i + (L-1)], only j<=i survives the causal mask.
//
// R2: whole low-precision path bf16 -> fp16. Scores stage in LDS as f16:
//     score buffer 64KB->33KB, total LDS ~37KB -> 4 blocks/CU (32 waves/CU, was 16).
//     Attacks remaining latency-boundedness (MfmaUtil 2.9%, VALUBusy 29%, HBM 22%,
//     Occ 38.7% -> nothing saturated; floor ~55us vs measured 180us).
//     fp16 also IMPROVES accuracy here (|scores|<~45, P in [0,1], 10 vs 7 mantissa
//     bits). Heavy tiles (qt large) dispatched first to shrink the tail.

#define Bq 4
#define Nh 16
#define Lq 1024
#define Dh 64
#define TQ 16     // query rows per block
#define NT 512    // 8 waves
#define LROW 1032 // f16 row stride (2064 B = 516 dw; 516%32=4 -> same bank geometry
                  // as the verified fp32 version; 16B-aligned for ds_read_b128)

typedef _Float16 h16;
typedef __attribute__((ext_vector_type(8))) _Float16 f16x8;
typedef __attribute__((ext_vector_type(4))) _Float16 f16x4;
typedef __attribute__((ext_vector_type(4))) float f32x4;

__device__ __forceinline__ f16x8 pack8h(float4 a, float4 b) {
    f16x8 o;
    o[0] = (h16)a.x; o[1] = (h16)a.y; o[2] = (h16)a.z; o[3] = (h16)a.w;
    o[4] = (h16)b.x; o[5] = (h16)b.y; o[6] = (h16)b.z; o[7] = (h16)b.w;
    return o;
}

__device__ __forceinline__ float wave_max(float v) {
    #pragma unroll
    for (int o = 32; o > 0; o >>= 1) v = fmaxf(v, __shfl_xor(v, o));
    return v;
}
__device__ __forceinline__ float wave_sum(float v) {
    #pragma unroll
    for (int o = 32; o > 0; o >>= 1) v += __shfl_xor(v, o);
    return v;
}

// ---------- prep: K and P fp32 -> f16 (one kernel, two ranges) ----------
__global__ __launch_bounds__(256) void cvt_kp_kernel(
    const float* __restrict__ K, const float* __restrict__ P,
    h16* __restrict__ Kb, h16* __restrict__ Pb)
{
    int b = blockIdx.x;
    const float* src; h16* dst; int idx;
    if (b < 4096) { idx = b * 256 + threadIdx.x; src = K; dst = Kb; }
    else          { idx = (b - 4096) * 256 + threadIdx.x; src = P; dst = Pb; }
    float4 v = ((const float4*)src)[idx];
    f16x4 o;
    o[0] = (h16)v.x; o[1] = (h16)v.y; o[2] = (h16)v.z; o[3] = (h16)v.w;
    ((f16x4*)dst)[idx] = o;
}

// ---------- prep: V [bn][j][d] fp32 -> Vt [bn][d][j] f16 ----------
__global__ __launch_bounds__(256) void vt_kernel(
    const float* __restrict__ V, h16* __restrict__ Vt)
{
    __shared__ float t[64][65];
    int bn = blockIdx.x >> 4, jt = blockIdx.x & 15;
    int tid = threadIdx.x;
    int d = tid & 63, q = tid >> 6;
    const float* vb = V + ((size_t)(bn * Lq + jt * 64)) * Dh;
    #pragma unroll
    for (int r = 0; r < 16; r++) {
        int jl = r * 4 + q;
        t[jl][d] = vb[(size_t)jl * Dh + d];
    }
    __syncthreads();
    int dd = tid >> 2, jb = (tid & 3) << 4;
    f16x8 s0, s1;
    #pragma unroll
    for (int jj = 0; jj < 8; jj++) {
        s0[jj] = (h16)t[jb + jj][dd];
        s1[jj] = (h16)t[jb + 8 + jj][dd];
    }
    h16* drow = Vt + (((size_t)(bn * 64 + dd)) << 10) + (jt << 6) + jb;
    *(f16x8*)drow = s0;
    *(f16x8*)(drow + 8) = s1;
}

// ---------- main ----------
__global__ __launch_bounds__(NT, 8) void relattn_kernel(
    const float* __restrict__ QC, const float* __restrict__ QP,
    const h16* __restrict__ Kb, const h16* __restrict__ Pb,
    const h16* __restrict__ Vtb,
    float* __restrict__ out, float* __restrict__ wout)
{
    __shared__ __align__(16) h16 s_s[TQ][LROW];     // 33024 B, f16 scores then f16 P
    __shared__ __align__(16) float dscr[4][64][4];  // 4096 B, Phase D split-k combine

    const int tid  = threadIdx.x;
    const int w    = tid >> 6, lane = tid & 63;
    const int ln   = lane & 15, quad = lane >> 4;

    // XCD-contiguous remap: 4096 blocks, 8 XCDs -> 512 consecutive work items per
    // XCD (all 64 query-tiles of bn 0..7 on XCD0, etc -> Kb/Vtb/Pb stay L2-hot).
    // Within XCD: heaviest tiles (qt large = long causal rows) first -> short tail.
    const int bidx = blockIdx.x;
    const int wg   = ((bidx & 7) << 9) | (bidx >> 3);
    const int bn   = wg >> 6, qt = 63 - (wg & 63);
    const int nh   = bn & 15;
    const int i0   = qt << 4, i1 = i0 + 15;

    // A fragments from fp32 directly: A[m=ln][k=quad*8+j]
    const float* qcrow = QC + (((size_t)(bn << 10) + i0 + ln) << 6) + (quad << 3);
    const float* qprow = QP + (((size_t)(bn << 10) + i0 + ln) << 6) + (quad << 3);
    f16x8 aC0 = pack8h(*(const float4*)qcrow,        *(const float4*)(qcrow + 4));
    f16x8 aC1 = pack8h(*(const float4*)(qcrow + 32), *(const float4*)(qcrow + 36));
    f16x8 aP0 = pack8h(*(const float4*)qprow,        *(const float4*)(qprow + 4));
    f16x8 aP1 = pack8h(*(const float4*)(qprow + 32), *(const float4*)(qprow + 36));

    // ---- Phase A: content scores S = QC . K^T (causal tiles only) ----
    const h16* kbase = Kb + (((size_t)(bn << 10)) << 6) + (quad << 3);
    #pragma unroll
    for (int ct = 0; ct < 8; ct++) {
        int c0 = ((ct << 3) + w) << 4;           // interleave tiles across 8 waves
        if (c0 <= i1) {
            const h16* kr = kbase + ((size_t)(c0 + ln) << 6);
            f32x4 acc = {0.f, 0.f, 0.f, 0.f};
            acc = __builtin_amdgcn_mfma_f32_16x16x32_f16(aC0, *(const f16x8*)kr,        acc, 0, 0, 0);
            acc = __builtin_amdgcn_mfma_f32_16x16x32_f16(aC1, *(const f16x8*)(kr + 32), acc, 0, 0, 0);
            #pragma unroll
            for (int rg = 0; rg < 4; rg++)        // C: col=ln, row=quad*4+rg
                s_s[(quad << 2) + rg][c0 + ln] = (h16)acc[rg];
        }
    }
    __syncthreads();

    // ---- Phase B: pos scores T = QP . P^T, scatter-add with rel_shift ----
    const h16* pbase = Pb + (((size_t)(nh << 10)) << 6) + (quad << 3);
    #pragma unroll
    for (int ct = 0; ct < 8; ct++) {
        int p0 = ((ct << 3) + w) << 4;
        if (p0 + i0 + 30 >= 1023) {              // some j = p+i-1023 >= 0 in tile
            const h16* pr = pbase + ((size_t)(p0 + ln) << 6);
            f32x4 acc = {0.f, 0.f, 0.f, 0.f};
            acc = __builtin_amdgcn_mfma_f32_16x16x32_f16(aP0, *(const f16x8*)pr,        acc, 0, 0, 0);
            acc = __builtin_amdgcn_mfma_f32_16x16x32_f16(aP1, *(const f16x8*)(pr + 32), acc, 0, 0, 0);
            int p = p0 + ln;
            #pragma unroll
            for (int rg = 0; rg < 4; rg++) {
                int row = (quad << 2) + rg;
                int j = p + i0 + row - 1023;     // j <= i always (p <= 1023)
                if (j >= 0)                      // unique (row,j) per lane: no race
                    s_s[row][j] = (h16)((float)s_s[row][j] + acc[rg]);
            }
        }
    }
    __syncthreads();

    // ---- Phase C: in-register softmax; write W fp32; pack f16 weights in-place ----
    // Wave w owns rows 2w, 2w+1. Lane owns j = c*256 + lane*4 + e, c=0..3, e=0..3.
    #pragma unroll
    for (int rr = 0; rr < 2; rr++) {
        int r = (w << 1) + rr;
        int i = i0 + r;
        float v[16];
        #pragma unroll
        for (int c = 0; c < 4; c++) {
            f16x4 t = *(f16x4*)&s_s[r][(c << 8) + (lane << 2)];
            v[c * 4 + 0] = (float)t[0]; v[c * 4 + 1] = (float)t[1];
            v[c * 4 + 2] = (float)t[2]; v[c * 4 + 3] = (float)t[3];
        }
        float mx = -3.0e38f;
        #pragma unroll
        for (int c = 0; c < 4; c++) {
            int j = (c << 8) + (lane << 2);
            #pragma unroll
            for (int e = 0; e < 4; e++)
                if (j + e <= i) mx = fmaxf(mx, v[c * 4 + e]);
        }
        mx = wave_max(mx);
        float sum = 0.f;
        #pragma unroll
        for (int c = 0; c < 4; c++) {
            int j = (c << 8) + (lane << 2);
            #pragma unroll
            for (int e = 0; e < 4; e++) {
                float t = (j + e <= i) ? __expf((v[c * 4 + e] - mx) * 0.125f) : 0.f;
                sum += t;
                v[c * 4 + e] = t;
            }
        }
        sum = wave_sum(sum);
        float inv = 1.0f / sum;
        float* wrow = wout + (((size_t)(bn << 10) + i) << 10);
        #pragma unroll
        for (int c = 0; c < 4; c++) {
            int j = (c << 8) + (lane << 2);
            float4 e;
            e.x = v[c * 4 + 0] * inv; e.y = v[c * 4 + 1] * inv;
            e.z = v[c * 4 + 2] * inv; e.w = v[c * 4 + 3] * inv;
            *(float4*)&wrow[j] = e;              // W output (coalesced, zeros in mask)
            f16x4 hh;
            hh[0] = (h16)e.x; hh[1] = (h16)e.y; hh[2] = (h16)e.z; hh[3] = (h16)e.w;
            *(f16x4*)&s_s[r][j] = hh;            // f16 A-operand for Phase D, in-place
        }
    }
    __syncthreads();

    // ---- Phase D: out = W . V via MFMA, split-k across wave pairs ----
    // Wave (w&3) owns output cols n0..n0+15; half h = w>>2 takes every other k-step.
    f32x4 o = {0.f, 0.f, 0.f, 0.f};
    const int n0 = (w & 3) << 4;
    const int h  = w >> 2;
    const h16* vtb = Vtb + (((size_t)(bn << 6) + n0 + ln) << 10);
    const h16* abase = &s_s[ln][0];
    const int ksteps = (i0 + 16 + 31) >> 5;       // j <= i1 only; rest of W is 0
    for (int ks = h; ks < ksteps; ks += 2) {
        int k0 = (ks << 5) + (quad << 3);
        f16x8 af = *(const f16x8*)(abase + k0);
        f16x8 vb = *(const f16x8*)(vtb + k0);
        o = __builtin_amdgcn_mfma_f32_16x16x32_f16(af, vb, o, 0, 0, 0);
    }
    if (h == 1)
        *(f32x4*)&dscr[w & 3][lane][0] = o;
    __syncthreads();
    if (h == 0) {
        f32x4 o2 = *(f32x4*)&dscr[w][lane][0];
        o[0] += o2[0]; o[1] += o2[1]; o[2] += o2[2]; o[3] += o2[3];
        float* obase = out + (((size_t)(bn << 10) + i0) << 6);
        #pragma unroll
        for (int rg = 0; rg < 4; rg++)
            obase[((size_t)((quad << 2) + rg) << 6) + n0 + ln] = o[rg];
    }
}

extern "C" void kernel_launch(void* const* d_in, const int* in_sizes, int n_in,
                              void* d_out, int out_size, void* d_ws, size_t ws_size,
                              hipStream_t stream) {
    const float* qc = (const float*)d_in[0];
    const float* qp = (const float*)d_in[1];
    const float* K  = (const float*)d_in[2];
    const float* V  = (const float*)d_in[3];
    const float* P  = (const float*)d_in[4];
    // d_in[5]: causal mask, hardcoded.

    float* out  = (float*)d_out;
    float* wout = out + (size_t)Bq * Nh * Lq * Dh;

    const size_t NQ = (size_t)Bq * Nh * Lq * Dh;   // 4,194,304
    const size_t NP = (size_t)Nh * Lq * Dh;        // 1,048,576
    h16* Kb  = (h16*)d_ws;
    h16* Pb  = Kb + NQ;
    h16* Vtb = Pb + NP;                            // total 18 MB of ws

    cvt_kp_kernel<<<4096 + 1024, 256, 0, stream>>>(K, P, Kb, Pb);
    vt_kernel<<<Bq * Nh * 16, 256, 0, stream>>>(V, Vtb);
    relattn_kernel<<<Bq * Nh * (Lq / TQ), NT, 0, stream>>>(qc, qp, Kb, Pb, Vtb, out, wout);
}

// Round 3
// 441.618 us; speedup vs baseline: 1.1038x; 1.0069x over previous
//
#include <hip/hip_runtime.h>
#include <math.h>

// Transformer-XL relative attention, fp16-MFMA, fused-softmax version.
// B=4 N=16 L=1024 D=64. Outputs: out [B,N,L,D] fp32, then weight [B,N,L,L] fp32.
// rel_shift(pos)[i,j] == pos[i, j - i + (L-1)], only j<=i survives the causal mask.
//
// R3: replace __syncthreads() (which compiles to s_waitcnt vmcnt(0) lgkmcnt(0) +
//     s_barrier -> every block drains its 64KB of W global stores before Phase D)
//     with lgkmcnt(0)-only + s_barrier. Cross-wave dependencies here are LDS-only;
//     global W/out stores have no in-kernel reader and may drain in background
//     under Phase D MFMA and the next block's Phase A. Theory: ~110us of the
//     ~170us runtime is vmcnt-drain convoy (4 resident blocks x 64KB at ~10B/cyc/CU
//     per round; occupancy cannot hide it since all waves convoy together).

#define Bq 4
#define Nh 16
#define Lq 1024
#define Dh 64
#define TQ 16     // query rows per block
#define NT 512    // 8 waves
#define LROW 1032 // f16 row stride (2064 B = 516 dw; 516%32=4 -> same bank geometry
                  // as the verified fp32 version; 16B-aligned for ds_read_b128)

// LDS-only barrier: wait for this wave's DS ops, then block barrier. Leaves
// global (vmcnt) traffic in flight across the barrier -- the whole point of R3.
#define BAR() asm volatile("s_waitcnt lgkmcnt(0)\n\ts_barrier" ::: "memory")

typedef _Float16 h16;
typedef __attribute__((ext_vector_type(8))) _Float16 f16x8;
typedef __attribute__((ext_vector_type(4))) _Float16 f16x4;
typedef __attribute__((ext_vector_type(4))) float f32x4;

__device__ __forceinline__ f16x8 pack8h(float4 a, float4 b) {
    f16x8 o;
    o[0] = (h16)a.x; o[1] = (h16)a.y; o[2] = (h16)a.z; o[3] = (h16)a.w;
    o[4] = (h16)b.x; o[5] = (h16)b.y; o[6] = (h16)b.z; o[7] = (h16)b.w;
    return o;
}

__device__ __forceinline__ float wave_max(float v) {
    #pragma unroll
    for (int o = 32; o > 0; o >>= 1) v = fmaxf(v, __shfl_xor(v, o));
    return v;
}
__device__ __forceinline__ float wave_sum(float v) {
    #pragma unroll
    for (int o = 32; o > 0; o >>= 1) v += __shfl_xor(v, o);
    return v;
}

// ---------- prep: K and P fp32 -> f16 (one kernel, two ranges) ----------
__global__ __launch_bounds__(256) void cvt_kp_kernel(
    const float* __restrict__ K, const float* __restrict__ P,
    h16* __restrict__ Kb, h16* __restrict__ Pb)
{
    int b = blockIdx.x;
    const float* src; h16* dst; int idx;
    if (b < 4096) { idx = b * 256 + threadIdx.x; src = K; dst = Kb; }
    else          { idx = (b - 4096) * 256 + threadIdx.x; src = P; dst = Pb; }
    float4 v = ((const float4*)src)[idx];
    f16x4 o;
    o[0] = (h16)v.x; o[1] = (h16)v.y; o[2] = (h16)v.z; o[3] = (h16)v.w;
    ((f16x4*)dst)[idx] = o;
}

// ---------- prep: V [bn][j][d] fp32 -> Vt [bn][d][j] f16 ----------
__global__ __launch_bounds__(256) void vt_kernel(
    const float* __restrict__ V, h16* __restrict__ Vt)
{
    __shared__ float t[64][65];
    int bn = blockIdx.x >> 4, jt = blockIdx.x & 15;
    int tid = threadIdx.x;
    int d = tid & 63, q = tid >> 6;
    const float* vb = V + ((size_t)(bn * Lq + jt * 64)) * Dh;
    #pragma unroll
    for (int r = 0; r < 16; r++) {
        int jl = r * 4 + q;
        t[jl][d] = vb[(size_t)jl * Dh + d];
    }
    __syncthreads();
    int dd = tid >> 2, jb = (tid & 3) << 4;
    f16x8 s0, s1;
    #pragma unroll
    for (int jj = 0; jj < 8; jj++) {
        s0[jj] = (h16)t[jb + jj][dd];
        s1[jj] = (h16)t[jb + 8 + jj][dd];
    }
    h16* drow = Vt + (((size_t)(bn * 64 + dd)) << 10) + (jt << 6) + jb;
    *(f16x8*)drow = s0;
    *(f16x8*)(drow + 8) = s1;
}

// ---------- main ----------
__global__ __launch_bounds__(NT, 8) void relattn_kernel(
    const float* __restrict__ QC, const float* __restrict__ QP,
    const h16* __restrict__ Kb, const h16* __restrict__ Pb,
    const h16* __restrict__ Vtb,
    float* __restrict__ out, float* __restrict__ wout)
{
    __shared__ __align__(16) h16 s_s[TQ][LROW];     // 33024 B, f16 scores then f16 P
    __shared__ __align__(16) float dscr[4][64][4];  // 4096 B, Phase D split-k combine

    const int tid  = threadIdx.x;
    const int w    = tid >> 6, lane = tid & 63;
    const int ln   = lane & 15, quad = lane >> 4;

    // XCD-contiguous remap: 4096 blocks, 8 XCDs -> 512 consecutive work items per
    // XCD (all 64 query-tiles of bn 0..7 on XCD0, etc -> Kb/Vtb/Pb stay L2-hot).
    // Within XCD: heaviest tiles (qt large = long causal rows) first -> short tail.
    const int bidx = blockIdx.x;
    const int wg   = ((bidx & 7) << 9) | (bidx >> 3);
    const int bn   = wg >> 6, qt = 63 - (wg & 63);
    const int nh   = bn & 15;
    const int i0   = qt << 4, i1 = i0 + 15;

    // A fragments from fp32 directly: A[m=ln][k=quad*8+j]
    const float* qcrow = QC + (((size_t)(bn << 10) + i0 + ln) << 6) + (quad << 3);
    const float* qprow = QP + (((size_t)(bn << 10) + i0 + ln) << 6) + (quad << 3);
    f16x8 aC0 = pack8h(*(const float4*)qcrow,        *(const float4*)(qcrow + 4));
    f16x8 aC1 = pack8h(*(const float4*)(qcrow + 32), *(const float4*)(qcrow + 36));
    f16x8 aP0 = pack8h(*(const float4*)qprow,        *(const float4*)(qprow + 4));
    f16x8 aP1 = pack8h(*(const float4*)(qprow + 32), *(const float4*)(qprow + 36));

    // ---- Phase A: content scores S = QC . K^T (causal tiles only) ----
    const h16* kbase = Kb + (((size_t)(bn << 10)) << 6) + (quad << 3);
    #pragma unroll
    for (int ct = 0; ct < 8; ct++) {
        int c0 = ((ct << 3) + w) << 4;           // interleave tiles across 8 waves
        if (c0 <= i1) {
            const h16* kr = kbase + ((size_t)(c0 + ln) << 6);
            f32x4 acc = {0.f, 0.f, 0.f, 0.f};
            acc = __builtin_amdgcn_mfma_f32_16x16x32_f16(aC0, *(const f16x8*)kr,        acc, 0, 0, 0);
            acc = __builtin_amdgcn_mfma_f32_16x16x32_f16(aC1, *(const f16x8*)(kr + 32), acc, 0, 0, 0);
            #pragma unroll
            for (int rg = 0; rg < 4; rg++)        // C: col=ln, row=quad*4+rg
                s_s[(quad << 2) + rg][c0 + ln] = (h16)acc[rg];
        }
    }
    BAR();

    // ---- Phase B: pos scores T = QP . P^T, scatter-add with rel_shift ----
    const h16* pbase = Pb + (((size_t)(nh << 10)) << 6) + (quad << 3);
    #pragma unroll
    for (int ct = 0; ct < 8; ct++) {
        int p0 = ((ct << 3) + w) << 4;
        if (p0 + i0 + 30 >= 1023) {              // some j = p+i-1023 >= 0 in tile
            const h16* pr = pbase + ((size_t)(p0 + ln) << 6);
            f32x4 acc = {0.f, 0.f, 0.f, 0.f};
            acc = __builtin_amdgcn_mfma_f32_16x16x32_f16(aP0, *(const f16x8*)pr,        acc, 0, 0, 0);
            acc = __builtin_amdgcn_mfma_f32_16x16x32_f16(aP1, *(const f16x8*)(pr + 32), acc, 0, 0, 0);
            int p = p0 + ln;
            #pragma unroll
            for (int rg = 0; rg < 4; rg++) {
                int row = (quad << 2) + rg;
                int j = p + i0 + row - 1023;     // j <= i always (p <= 1023)
                if (j >= 0)                      // unique (row,j) per lane: no race
                    s_s[row][j] = (h16)((float)s_s[row][j] + acc[rg]);
            }
        }
    }
    BAR();

    // ---- Phase C: in-register softmax; write W fp32; pack f16 weights in-place ----
    // Wave w owns rows 2w, 2w+1. Lane owns j = c*256 + lane*4 + e, c=0..3, e=0..3.
    #pragma unroll
    for (int rr = 0; rr < 2; rr++) {
        int r = (w << 1) + rr;
        int i = i0 + r;
        float v[16];
        #pragma unroll
        for (int c = 0; c < 4; c++) {
            f16x4 t = *(f16x4*)&s_s[r][(c << 8) + (lane << 2)];
            v[c * 4 + 0] = (float)t[0]; v[c * 4 + 1] = (float)t[1];
            v[c * 4 + 2] = (float)t[2]; v[c * 4 + 3] = (float)t[3];
        }
        float mx = -3.0e38f;
        #pragma unroll
        for (int c = 0; c < 4; c++) {
            int j = (c << 8) + (lane << 2);
            #pragma unroll
            for (int e = 0; e < 4; e++)
                if (j + e <= i) mx = fmaxf(mx, v[c * 4 + e]);
        }
        mx = wave_max(mx);
        float sum = 0.f;
        #pragma unroll
        for (int c = 0; c < 4; c++) {
            int j = (c << 8) + (lane << 2);
            #pragma unroll
            for (int e = 0; e < 4; e++) {
                float t = (j + e <= i) ? __expf((v[c * 4 + e] - mx) * 0.125f) : 0.f;
                sum += t;
                v[c * 4 + e] = t;
            }
        }
        sum = wave_sum(sum);
        float inv = 1.0f / sum;
        float* wrow = wout + (((size_t)(bn << 10) + i) << 10);
        #pragma unroll
        for (int c = 0; c < 4; c++) {
            int j = (c << 8) + (lane << 2);
            float4 e;
            e.x = v[c * 4 + 0] * inv; e.y = v[c * 4 + 1] * inv;
            e.z = v[c * 4 + 2] * inv; e.w = v[c * 4 + 3] * inv;
            *(float4*)&wrow[j] = e;              // W output: fire-and-forget, drains
                                                 // in background past the barriers
            f16x4 hh;
            hh[0] = (h16)e.x; hh[1] = (h16)e.y; hh[2] = (h16)e.z; hh[3] = (h16)e.w;
            *(f16x4*)&s_s[r][j] = hh;            // f16 A-operand for Phase D, in-place
        }
    }
    BAR();

    // ---- Phase D: out = W . V via MFMA, split-k across wave pairs ----
    // Wave (w&3) owns output cols n0..n0+15; half h = w>>2 takes every other k-step.
    f32x4 o = {0.f, 0.f, 0.f, 0.f};
    const int n0 = (w & 3) << 4;
    const int h  = w >> 2;
    const h16* vtb = Vtb + (((size_t)(bn << 6) + n0 + ln) << 10);
    const h16* abase = &s_s[ln][0];
    const int ksteps = (i0 + 16 + 31) >> 5;       // j <= i1 only; rest of W is 0
    for (int ks = h; ks < ksteps; ks += 2) {
        int k0 = (ks << 5) + (quad << 3);
        f16x8 af = *(const f16x8*)(abase + k0);
        f16x8 vb = *(const f16x8*)(vtb + k0);
        o = __builtin_amdgcn_mfma_f32_16x16x32_f16(af, vb, o, 0, 0, 0);
    }
    if (h == 1)
        *(f32x4*)&dscr[w & 3][lane][0] = o;
    BAR();
    if (h == 0) {
        f32x4 o2 = *(f32x4*)&dscr[w][lane][0];
        o[0] += o2[0]; o[1] += o2[1]; o[2] += o2[2]; o[3] += o2[3];
        float* obase = out + (((size_t)(bn << 10) + i0) << 6);
        #pragma unroll
        for (int rg = 0; rg < 4; rg++)
            obase[((size_t)((quad << 2) + rg) << 6) + n0 + ln] = o[rg];
    }
}

extern "C" void kernel_launch(void* const* d_in, const int* in_sizes, int n_in,
                              void* d_out, int out_size, void* d_ws, size_t ws_size,
                              hipStream_t stream) {
    const float* qc = (const float*)d_in[0];
    const float* qp = (const float*)d_in[1];
    const float* K  = (const float*)d_in[2];
    const float* V  = (const float*)d_in[3];
    const float* P  = (const float*)d_in[4];
    // d_in[5]: causal mask, hardcoded.

    float* out  = (float*)d_out;
    float* wout = out + (size_t)Bq * Nh * Lq * Dh;

    const size_t NQ = (size_t)Bq * Nh * Lq * Dh;   // 4,194,304
    const size_t NP = (size_t)Nh * Lq * Dh;        // 1,048,576
    h16* Kb  = (h16*)d_ws;
    h16* Pb  = Kb + NQ;
    h16* Vtb = Pb + NP;                            // total 18 MB of ws

    cvt_kp_kernel<<<4096 + 1024, 256, 0, stream>>>(K, P, Kb, Pb);
    vt_kernel<<<Bq * Nh * 16, 256, 0, stream>>>(V, Vtb);
    relattn_kernel<<<Bq * Nh * (Lq / TQ), NT, 0, stream>>>(qc, qp, Kb, Pb, Vtb, out, wout);
}

// Round 5
// 432.507 us; speedup vs baseline: 1.1271x; 1.0211x over previous
//
#include <hip/hip_runtime.h>
#include <math.h>

// Transformer-XL relative attention, fp16-MFMA, fused-softmax version.
// B=4 N=16 L=1024 D=64. Outputs: out [B,N,L,D] fp32, then weight [B,N,L,L] fp32.
// rel_shift(pos)[i,j] == pos[i, j - i + (L-1)], only j<=i survives the causal mask.
//
// R5 (= R4 with compile fix: nontemporal builtin needs ext-vector, not HIP float4):
//     (a) maskless softmax -- Phase A cndmasks the diagonal tile to -inf at store,
//     a vectorized -inf fill covers never-written cols j>i1, so Phase C drops all
//     64 per-row cmp+cndmask ops (exp(-inf)=0 gives W's exact zeros); v_rcp for
//     1/sum. (b) non-temporal stores for W (256MB write-once) + out: bypass L2 so
//     Kb/Vtb/Pb stay L2-resident instead of churning under W write-back.
//     (c) prep kernels merged into one dispatch. R3 falsified store-drain theory
//     (lgkm-only barriers: -3us); remaining suspects = VALU volume + L2 pollution.

#define Bq 4
#define Nh 16
#define Lq 1024
#define Dh 64
#define TQ 16     // query rows per block
#define NT 512    // 8 waves
#define LROW 1032 // f16 row stride (2064 B = 516 dw; 516%32=4 -> 2-way banks, free;
                  // 16B-aligned for ds_read_b128)

// LDS-only barrier: wait for this wave's DS ops, then block barrier. Leaves
// global (vmcnt) traffic in flight across the barrier.
#define BAR() asm volatile("s_waitcnt lgkmcnt(0)\n\ts_barrier" ::: "memory")

typedef _Float16 h16;
typedef __attribute__((ext_vector_type(8))) _Float16 f16x8;
typedef __attribute__((ext_vector_type(4))) _Float16 f16x4;
typedef __attribute__((ext_vector_type(4))) float f32x4;

__device__ __forceinline__ f16x8 pack8h(float4 a, float4 b) {
    f16x8 o;
    o[0] = (h16)a.x; o[1] = (h16)a.y; o[2] = (h16)a.z; o[3] = (h16)a.w;
    o[4] = (h16)b.x; o[5] = (h16)b.y; o[6] = (h16)b.z; o[7] = (h16)b.w;
    return o;
}

__device__ __forceinline__ float wave_max(float v) {
    #pragma unroll
    for (int o = 32; o > 0; o >>= 1) v = fmaxf(v, __shfl_xor(v, o));
    return v;
}
__device__ __forceinline__ float wave_sum(float v) {
    #pragma unroll
    for (int o = 32; o > 0; o >>= 1) v += __shfl_xor(v, o);
    return v;
}

// ---------- prep (single dispatch): cvt K,P -> f16; transpose V -> Vt f16 ----------
// blocks 0..4095: K cvt; 4096..5119: P cvt; 5120..6143: V transpose.
__global__ __launch_bounds__(256) void prep_kernel(
    const float* __restrict__ K, const float* __restrict__ P,
    const float* __restrict__ V,
    h16* __restrict__ Kb, h16* __restrict__ Pb, h16* __restrict__ Vt)
{
    __shared__ float t[64][65];
    int b = blockIdx.x;
    if (b < 5120) {
        const float* src; h16* dst; int idx;
        if (b < 4096) { idx = b * 256 + threadIdx.x; src = K; dst = Kb; }
        else          { idx = (b - 4096) * 256 + threadIdx.x; src = P; dst = Pb; }
        float4 v = ((const float4*)src)[idx];
        f16x4 o;
        o[0] = (h16)v.x; o[1] = (h16)v.y; o[2] = (h16)v.z; o[3] = (h16)v.w;
        ((f16x4*)dst)[idx] = o;
        return;
    }
    int bv = b - 5120;
    int bn = bv >> 4, jt = bv & 15;
    int tid = threadIdx.x;
    int d = tid & 63, q = tid >> 6;
    const float* vb = V + ((size_t)(bn * Lq + jt * 64)) * Dh;
    #pragma unroll
    for (int r = 0; r < 16; r++) {
        int jl = r * 4 + q;
        t[jl][d] = vb[(size_t)jl * Dh + d];
    }
    __syncthreads();
    int dd = tid >> 2, jb = (tid & 3) << 4;
    f16x8 s0, s1;
    #pragma unroll
    for (int jj = 0; jj < 8; jj++) {
        s0[jj] = (h16)t[jb + jj][dd];
        s1[jj] = (h16)t[jb + 8 + jj][dd];
    }
    h16* drow = Vt + (((size_t)(bn * 64 + dd)) << 10) + (jt << 6) + jb;
    *(f16x8*)drow = s0;
    *(f16x8*)(drow + 8) = s1;
}

// ---------- main ----------
__global__ __launch_bounds__(NT, 8) void relattn_kernel(
    const float* __restrict__ QC, const float* __restrict__ QP,
    const h16* __restrict__ Kb, const h16* __restrict__ Pb,
    const h16* __restrict__ Vtb,
    float* __restrict__ out, float* __restrict__ wout)
{
    __shared__ __align__(16) h16 s_s[TQ][LROW];     // 33024 B, f16 scores then f16 W
    __shared__ __align__(16) float dscr[4][64][4];  // 4096 B, Phase D split-k combine

    const int tid  = threadIdx.x;
    const int w    = tid >> 6, lane = tid & 63;
    const int ln   = lane & 15, quad = lane >> 4;

    // XCD-contiguous remap: 4096 blocks, 8 XCDs -> 512 consecutive work items per
    // XCD (all 64 query-tiles of bn 0..7 on XCD0, etc -> Kb/Vtb/Pb stay L2-hot).
    // Within XCD: heaviest tiles (qt large = long causal rows) first -> short tail.
    const int bidx = blockIdx.x;
    const int wg   = ((bidx & 7) << 9) | (bidx >> 3);
    const int bn   = wg >> 6, qt = 63 - (wg & 63);
    const int nh   = bn & 15;
    const int i0   = qt << 4, i1 = i0 + 15;

    // A fragments from fp32 directly: A[m=ln][k=quad*8+j]
    const float* qcrow = QC + (((size_t)(bn << 10) + i0 + ln) << 6) + (quad << 3);
    const float* qprow = QP + (((size_t)(bn << 10) + i0 + ln) << 6) + (quad << 3);
    f16x8 aC0 = pack8h(*(const float4*)qcrow,        *(const float4*)(qcrow + 4));
    f16x8 aC1 = pack8h(*(const float4*)(qcrow + 32), *(const float4*)(qcrow + 36));
    f16x8 aP0 = pack8h(*(const float4*)qprow,        *(const float4*)(qprow + 4));
    f16x8 aP1 = pack8h(*(const float4*)(qprow + 32), *(const float4*)(qprow + 36));

    // -inf fill of the never-written region j in [i1+1, 1024): 4 rows per
    // 128-thread group, f16x8 stores. Makes Phase C maskless (exp(-inf)=0).
    {
        f16x8 nf;
        #pragma unroll
        for (int k = 0; k < 8; k++) nf[k] = (h16)-INFINITY;
        int rr0 = tid >> 7;             // 0..3
        int tt  = tid & 127;            // 0..127
        int col = i0 + 16 + (tt << 3);
        if (col < 1024) {
            #pragma unroll
            for (int r = rr0; r < 16; r += 4)
                *(f16x8*)&s_s[r][col] = nf;
        }
    }

    // ---- Phase A: content scores S = QC . K^T (causal tiles only) ----
    // Diagonal tile (c0 == i0) masked to -inf at store: j > i -> -inf.
    const h16* kbase = Kb + (((size_t)(bn << 10)) << 6) + (quad << 3);
    #pragma unroll
    for (int ct = 0; ct < 8; ct++) {
        int c0 = ((ct << 3) + w) << 4;           // interleave tiles across 8 waves
        if (c0 <= i1) {
            const h16* kr = kbase + ((size_t)(c0 + ln) << 6);
            f32x4 acc = {0.f, 0.f, 0.f, 0.f};
            acc = __builtin_amdgcn_mfma_f32_16x16x32_f16(aC0, *(const f16x8*)kr,        acc, 0, 0, 0);
            acc = __builtin_amdgcn_mfma_f32_16x16x32_f16(aC1, *(const f16x8*)(kr + 32), acc, 0, 0, 0);
            #pragma unroll
            for (int rg = 0; rg < 4; rg++) {      // C: col=ln, row=quad*4+rg
                int row = (quad << 2) + rg;
                float val = (c0 + ln <= i0 + row) ? acc[rg] : -INFINITY;
                s_s[row][c0 + ln] = (h16)val;
            }
        }
    }
    BAR();

    // ---- Phase B: pos scores T = QP . P^T, scatter-add with rel_shift ----
    const h16* pbase = Pb + (((size_t)(nh << 10)) << 6) + (quad << 3);
    #pragma unroll
    for (int ct = 0; ct < 8; ct++) {
        int p0 = ((ct << 3) + w) << 4;
        if (p0 + i0 + 30 >= 1023) {              // some j = p+i-1023 >= 0 in tile
            const h16* pr = pbase + ((size_t)(p0 + ln) << 6);
            f32x4 acc = {0.f, 0.f, 0.f, 0.f};
            acc = __builtin_amdgcn_mfma_f32_16x16x32_f16(aP0, *(const f16x8*)pr,        acc, 0, 0, 0);
            acc = __builtin_amdgcn_mfma_f32_16x16x32_f16(aP1, *(const f16x8*)(pr + 32), acc, 0, 0, 0);
            int p = p0 + ln;
            #pragma unroll
            for (int rg = 0; rg < 4; rg++) {
                int row = (quad << 2) + rg;
                int j = p + i0 + row - 1023;     // j <= i always (p <= 1023)
                if (j >= 0)                      // unique (row,j) per lane: no race
                    s_s[row][j] = (h16)((float)s_s[row][j] + acc[rg]);
            }
        }
    }
    BAR();

    // ---- Phase C: maskless in-register softmax; nt-store W fp32; pack f16 ----
    // Wave w owns rows 2w, 2w+1. Lane owns j = c*256 + lane*4 + e, c=0..3, e=0..3.
    #pragma unroll
    for (int rr = 0; rr < 2; rr++) {
        int r = (w << 1) + rr;
        int i = i0 + r;
        float v[16];
        #pragma unroll
        for (int c = 0; c < 4; c++) {
            f16x4 t = *(f16x4*)&s_s[r][(c << 8) + (lane << 2)];
            v[c * 4 + 0] = (float)t[0]; v[c * 4 + 1] = (float)t[1];
            v[c * 4 + 2] = (float)t[2]; v[c * 4 + 3] = (float)t[3];
        }
        float mx = v[0];
        #pragma unroll
        for (int k = 1; k < 16; k++) mx = fmaxf(mx, v[k]);
        mx = wave_max(mx);                       // real: row always has j=0 live
        float sum = 0.f;
        #pragma unroll
        for (int k = 0; k < 16; k++) {
            float t = __expf((v[k] - mx) * 0.125f);   // exp(-inf)=0: exact mask zeros
            sum += t;
            v[k] = t;
        }
        sum = wave_sum(sum);
        float inv = __builtin_amdgcn_rcpf(sum);
        float* wrow = wout + (((size_t)(bn << 10) + i) << 10);
        #pragma unroll
        for (int c = 0; c < 4; c++) {
            int j = (c << 8) + (lane << 2);
            f32x4 e;
            e[0] = v[c * 4 + 0] * inv; e[1] = v[c * 4 + 1] * inv;
            e[2] = v[c * 4 + 2] * inv; e[3] = v[c * 4 + 3] * inv;
            __builtin_nontemporal_store(e, (f32x4*)&wrow[j]);  // W: write-once, skip L2
            f16x4 hh;
            hh[0] = (h16)e[0]; hh[1] = (h16)e[1]; hh[2] = (h16)e[2]; hh[3] = (h16)e[3];
            *(f16x4*)&s_s[r][j] = hh;            // f16 A-operand for Phase D, in-place
        }
    }
    BAR();

    // ---- Phase D: out = W . V via MFMA, split-k across wave pairs ----
    // Wave (w&3) owns output cols n0..n0+15; half h = w>>2 takes every other k-step.
    f32x4 o = {0.f, 0.f, 0.f, 0.f};
    const int n0 = (w & 3) << 4;
    const int h  = w >> 2;
    const h16* vtb = Vtb + (((size_t)(bn << 6) + n0 + ln) << 10);
    const h16* abase = &s_s[ln][0];
    const int ksteps = (i0 + 16 + 31) >> 5;       // j <= i1 only; rest of W is 0
    for (int ks = h; ks < ksteps; ks += 2) {
        int k0 = (ks << 5) + (quad << 3);
        f16x8 af = *(const f16x8*)(abase + k0);
        f16x8 vb = *(const f16x8*)(vtb + k0);
        o = __builtin_amdgcn_mfma_f32_16x16x32_f16(af, vb, o, 0, 0, 0);
    }
    if (h == 1)
        *(f32x4*)&dscr[w & 3][lane][0] = o;
    BAR();
    if (h == 0) {
        f32x4 o2 = *(f32x4*)&dscr[w][lane][0];
        o[0] += o2[0]; o[1] += o2[1]; o[2] += o2[2]; o[3] += o2[3];
        float* obase = out + (((size_t)(bn << 10) + i0) << 6);
        #pragma unroll
        for (int rg = 0; rg < 4; rg++)
            __builtin_nontemporal_store(
                o[rg], &obase[((size_t)((quad << 2) + rg) << 6) + n0 + ln]);
    }
}

extern "C" void kernel_launch(void* const* d_in, const int* in_sizes, int n_in,
                              void* d_out, int out_size, void* d_ws, size_t ws_size,
                              hipStream_t stream) {
    const float* qc = (const float*)d_in[0];
    const float* qp = (const float*)d_in[1];
    const float* K  = (const float*)d_in[2];
    const float* V  = (const float*)d_in[3];
    const float* P  = (const float*)d_in[4];
    // d_in[5]: causal mask, hardcoded.

    float* out  = (float*)d_out;
    float* wout = out + (size_t)Bq * Nh * Lq * Dh;

    const size_t NQ = (size_t)Bq * Nh * Lq * Dh;   // 4,194,304
    const size_t NP = (size_t)Nh * Lq * Dh;        // 1,048,576
    h16* Kb  = (h16*)d_ws;
    h16* Pb  = Kb + NQ;
    h16* Vtb = Pb + NP;                            // total 18 MB of ws

    prep_kernel<<<4096 + 1024 + 1024, 256, 0, stream>>>(K, P, V, Kb, Pb, Vtb);
    relattn_kernel<<<Bq * Nh * (Lq / TQ), NT, 0, stream>>>(qc, qp, Kb, Pb, Vtb, out, wout);
}